// Round 1
// baseline (86.778 us; speedup 1.0000x reference)
//
#include <hip/hip_runtime.h>
#include <math.h>

#define NQ 8
#define DEPTH 3
#define FDIM 16
#define HDIM 256
#define WAVES_PER_BLOCK 4
#define THREADS (WAVES_PER_BLOCK * 64)
#define NPARAM (2 * NQ * DEPTH)   // 48

__device__ __forceinline__ float wave_reduce_sum(float v) {
#pragma unroll
    for (int off = 1; off < 64; off <<= 1)
        v += __shfl_xor(v, off, 64);
    return v;
}

__global__ __launch_bounds__(THREADS) void hqcl_kernel(
    const float* __restrict__ x,     // (B,16)
    const float* __restrict__ w1,    // (256,16)
    const float* __restrict__ b1,    // (256)
    const float* __restrict__ w2,    // (8,256)
    const float* __restrict__ b2,    // (8)
    const float* __restrict__ qp,    // (48)
    const float* __restrict__ dw1,   // (256,1)
    const float* __restrict__ db1,   // (256)
    const float* __restrict__ dw2,   // (1,256)
    const float* __restrict__ db2,   // (1)
    float* __restrict__ out, int B)
{
    __shared__ float sW1T[FDIM * HDIM];   // [k][j] transposed
    __shared__ float sB1[HDIM];
    __shared__ float sW2[NQ * HDIM];      // [q][j]
    __shared__ float sB2[NQ];
    __shared__ float sQc[NPARAM], sQs[NPARAM];
    __shared__ float sDw1[HDIM], sDb1[HDIM], sDw2[HDIM];
    __shared__ float sDb2;

    const int t = threadIdx.x;

    // ---- stage weights to LDS ----
    for (int idx = t; idx < FDIM * HDIM; idx += THREADS) {
        int j = idx >> 4, k = idx & 15;
        sW1T[k * HDIM + j] = w1[idx];
    }
    for (int idx = t; idx < NQ * HDIM; idx += THREADS) sW2[idx] = w2[idx];
    if (t < HDIM) {
        sB1[t]  = b1[t];
        sDw1[t] = dw1[t];
        sDb1[t] = db1[t];
        sDw2[t] = dw2[t];
    }
    if (t < NQ) sB2[t] = b2[t];
    if (t < NPARAM) {
        float s, c;
        __sincosf(qp[t] * 0.5f, &s, &c);
        sQc[t] = c; sQs[t] = s;
    }
    if (t == 0) sDb2 = db2[0];
    __syncthreads();

    const int wave = t >> 6;
    const int lane = t & 63;
    const int row  = blockIdx.x * WAVES_PER_BLOCK + wave;
    if (row >= B) return;

    // ---- encoder: h = relu(x @ W1^T + b1); angles = tanh(h @ W2^T + b2) * pi ----
    const float* xr = x + row * FDIM;
    float xv[FDIM];
#pragma unroll
    for (int k = 0; k < FDIM; k++) xv[k] = xr[k];

    float hreg[4];
#pragma unroll
    for (int m = 0; m < 4; m++) {
        int j = lane + 64 * m;
        float acc = sB1[j];
#pragma unroll
        for (int k = 0; k < FDIM; k++) acc = fmaf(xv[k], sW1T[k * HDIM + j], acc);
        hreg[m] = fmaxf(acc, 0.f);
    }

    float c0[NQ], s0[NQ];
#pragma unroll
    for (int q = 0; q < NQ; q++) {
        float a = 0.f;
#pragma unroll
        for (int m = 0; m < 4; m++) a = fmaf(hreg[m], sW2[q * HDIM + lane + 64 * m], a);
        a = wave_reduce_sum(a);
        float ang = tanhf(a + sB2[q]) * 3.14159265358979323846f;
        __sincosf(ang * 0.5f, &s0[q], &c0[q]);
    }

    // ---- quantum sim: state in 4 complex regs per lane, amp index a = hi*64 + lane ----
    // qubit q <-> bit (7-q); bits 0..5 = lane bits, bit6 = hi&1, bit7 = hi>>1.
    // initial 8 RYs on |0..0> -> product state
    float pl = 1.f;
#pragma unroll
    for (int b = 0; b < 6; b++) {
        int q = 7 - b;
        pl *= ((lane >> b) & 1) ? s0[q] : c0[q];
    }
    float sr[4], si[4];
    sr[0] = pl * c0[1] * c0[0];
    sr[1] = pl * s0[1] * c0[0];
    sr[2] = pl * c0[1] * s0[0];
    sr[3] = pl * s0[1] * s0[0];
#pragma unroll
    for (int hi = 0; hi < 4; hi++) si[hi] = 0.f;

#pragma unroll
    for (int layer = 0; layer < DEPTH; layer++) {
#pragma unroll
        for (int q = 0; q < NQ; q++) {
            const int b = 7 - q;
            // ---- RZ(qp[layer*16+2q], q) ----
            {
                float cz = sQc[layer * 16 + 2 * q], sz = sQs[layer * 16 + 2 * q];
                if (b < 6) {
                    float sg = ((lane >> b) & 1) ? sz : -sz;
#pragma unroll
                    for (int hi = 0; hi < 4; hi++) {
                        float nr = sr[hi] * cz - si[hi] * sg;
                        float ni = sr[hi] * sg + si[hi] * cz;
                        sr[hi] = nr; si[hi] = ni;
                    }
                } else {
#pragma unroll
                    for (int hi = 0; hi < 4; hi++) {
                        int bit = (b == 6) ? (hi & 1) : (hi >> 1);
                        float sg = bit ? sz : -sz;
                        float nr = sr[hi] * cz - si[hi] * sg;
                        float ni = sr[hi] * sg + si[hi] * cz;
                        sr[hi] = nr; si[hi] = ni;
                    }
                }
            }
            // ---- RY(qp[layer*16+2q+1], q) ----
            {
                float cy = sQc[layer * 16 + 2 * q + 1], sy = sQs[layer * 16 + 2 * q + 1];
                if (b < 6) {
                    float sg = ((lane >> b) & 1) ? sy : -sy;
#pragma unroll
                    for (int hi = 0; hi < 4; hi++) {
                        float pr = __shfl_xor(sr[hi], 1 << b, 64);
                        float pi = __shfl_xor(si[hi], 1 << b, 64);
                        sr[hi] = fmaf(sg, pr, cy * sr[hi]);
                        si[hi] = fmaf(sg, pi, cy * si[hi]);
                    }
                } else if (b == 6) {
                    // pairs (0,1),(2,3)
#pragma unroll
                    for (int p = 0; p < 2; p++) {
                        int a0 = 2 * p, a1 = 2 * p + 1;
                        float nr0 = cy * sr[a0] - sy * sr[a1];
                        float ni0 = cy * si[a0] - sy * si[a1];
                        float nr1 = sy * sr[a0] + cy * sr[a1];
                        float ni1 = sy * si[a0] + cy * si[a1];
                        sr[a0] = nr0; si[a0] = ni0; sr[a1] = nr1; si[a1] = ni1;
                    }
                } else {
                    // pairs (0,2),(1,3)
#pragma unroll
                    for (int p = 0; p < 2; p++) {
                        int a0 = p, a1 = p + 2;
                        float nr0 = cy * sr[a0] - sy * sr[a1];
                        float ni0 = cy * si[a0] - sy * si[a1];
                        float nr1 = sy * sr[a0] + cy * sr[a1];
                        float ni1 = sy * si[a0] + cy * si[a1];
                        sr[a0] = nr0; si[a0] = ni0; sr[a1] = nr1; si[a1] = ni1;
                    }
                }
            }
        }
        // ---- CX chain: CX(i, (i+1)%8), qubit i -> bit 7-i ----
        // i=0: ctrl bit7, tgt bit6 -> swap regs 2,3
        {
            float tr = sr[2], ti = si[2];
            sr[2] = sr[3]; si[2] = si[3];
            sr[3] = tr;    si[3] = ti;
        }
        // i=1: ctrl bit6 (hi&1), tgt bit5 -> regs 1,3 shfl_xor 32
        sr[1] = __shfl_xor(sr[1], 32, 64); si[1] = __shfl_xor(si[1], 32, 64);
        sr[3] = __shfl_xor(sr[3], 32, 64); si[3] = __shfl_xor(si[3], 32, 64);
        // i=2..6: ctrl lane bit (7-i), tgt lane bit (6-i)
#pragma unroll
        for (int i2 = 2; i2 < 7; i2++) {
            const int bc = 7 - i2, bt = 6 - i2;
            bool ctrl = (lane >> bc) & 1;
#pragma unroll
            for (int hi = 0; hi < 4; hi++) {
                float pr = __shfl_xor(sr[hi], 1 << bt, 64);
                float pi = __shfl_xor(si[hi], 1 << bt, 64);
                sr[hi] = ctrl ? pr : sr[hi];
                si[hi] = ctrl ? pi : si[hi];
            }
        }
        // i=7: ctrl lane bit0, tgt bit7 -> swap (0,2),(1,3) where ctrl
        {
            bool ctrl = lane & 1;
            float t0r = sr[0], t0i = si[0], t1r = sr[1], t1i = si[1];
            sr[0] = ctrl ? sr[2] : sr[0]; si[0] = ctrl ? si[2] : si[0];
            sr[2] = ctrl ? t0r : sr[2];   si[2] = ctrl ? t0i : si[2];
            sr[1] = ctrl ? sr[3] : sr[1]; si[1] = ctrl ? si[3] : si[1];
            sr[3] = ctrl ? t1r : sr[3];   si[3] = ctrl ? t1i : si[3];
        }
    }

    // ---- expectation <Z_0>: + for hi in {0,1}, - for hi in {2,3} ----
    float e = sr[0] * sr[0] + si[0] * si[0] + sr[1] * sr[1] + si[1] * si[1]
            - sr[2] * sr[2] - si[2] * si[2] - sr[3] * sr[3] - si[3] * si[3];
    e = wave_reduce_sum(e);

    // ---- decoder: sigmoid( sum_j relu(e*dw1[j]+db1[j]) * dw2[j] + db2 ) ----
    float acc = 0.f;
#pragma unroll
    for (int m = 0; m < 4; m++) {
        int j = lane + 64 * m;
        float d = fmaxf(fmaf(e, sDw1[j], sDb1[j]), 0.f);
        acc = fmaf(d, sDw2[j], acc);
    }
    acc = wave_reduce_sum(acc);
    if (lane == 0) out[row] = 1.f / (1.f + __expf(-(acc + sDb2)));
}

extern "C" void kernel_launch(void* const* d_in, const int* in_sizes, int n_in,
                              void* d_out, int out_size, void* d_ws, size_t ws_size,
                              hipStream_t stream) {
    const float* x   = (const float*)d_in[0];
    const float* w1  = (const float*)d_in[1];
    const float* b1  = (const float*)d_in[2];
    const float* w2  = (const float*)d_in[3];
    const float* b2  = (const float*)d_in[4];
    const float* qp  = (const float*)d_in[5];
    const float* dw1 = (const float*)d_in[6];
    const float* db1 = (const float*)d_in[7];
    const float* dw2 = (const float*)d_in[8];
    const float* db2 = (const float*)d_in[9];
    float* out = (float*)d_out;

    const int B = in_sizes[0] / FDIM;
    const int grid = (B + WAVES_PER_BLOCK - 1) / WAVES_PER_BLOCK;
    hqcl_kernel<<<grid, THREADS, 0, stream>>>(x, w1, b1, w2, b2, qp, dw1, db1, dw2, db2, out, B);
}

// Round 3
// 61.359 us; speedup vs baseline: 1.4143x; 1.4143x over previous
//
#include <hip/hip_runtime.h>
#include <math.h>

#define NQ 8
#define DEPTH 3
#define FDIM 16
#define HDIM 256
#define WAVES_PER_BLOCK 4
#define THREADS (WAVES_PER_BLOCK * 64)
#define NPARAM (2 * NQ * DEPTH)   // 48

// ---------------- cross-lane xor shuffles, all VALU-rate (no LDS) ----------------
template<int CTRL>
__device__ __forceinline__ float dpp1(float v) {
    return __int_as_float(__builtin_amdgcn_update_dpp(
        0, __float_as_int(v), CTRL, 0xF, 0xF, true));
}

template<int MASK>
__device__ __forceinline__ float sx(float v, int lane) {
    if constexpr (MASK == 1)  return dpp1<0xB1>(v);            // quad_perm [1,0,3,2] = xor1
    else if constexpr (MASK == 2)  return dpp1<0x4E>(v);       // quad_perm [2,3,0,1] = xor2
    else if constexpr (MASK == 4)  return dpp1<0x1B>(dpp1<0x141>(v)); // xor3 o xor7 = xor4
    else if constexpr (MASK == 8)  return dpp1<0x128>(v);      // row_ror:8 == xor8
    else if constexpr (MASK == 16) {
#if __has_builtin(__builtin_amdgcn_permlane16_swap)
        // r[0] = rows {0,0,2,2} of v ; r[1] = rows {1,1,3,3} of v
        auto r = __builtin_amdgcn_permlane16_swap(__float_as_int(v), __float_as_int(v), false, false);
        return __int_as_float((lane & 16) ? r[0] : r[1]);
#else
        return __shfl_xor(v, 16, 64);
#endif
    } else if constexpr (MASK == 32) {
#if __has_builtin(__builtin_amdgcn_permlane32_swap)
        // r[0] = {lo,lo} of v ; r[1] = {hi,hi} of v
        auto r = __builtin_amdgcn_permlane32_swap(__float_as_int(v), __float_as_int(v), false, false);
        return __int_as_float((lane & 32) ? r[0] : r[1]);
#else
        return __shfl_xor(v, 32, 64);
#endif
    } else {
        return v;
    }
}

__device__ __forceinline__ float wred(float v, int lane) {
    v += sx<1>(v, lane);
    v += sx<2>(v, lane);
    v += sx<4>(v, lane);
    v += sx<8>(v, lane);
    v += sx<16>(v, lane);
    v += sx<32>(v, lane);
    return v;
}

// ---------------- gate helpers (state: 4 complex regs, amp = hi*64 + lane) ----------------
// qubit q <-> bit (7-q); bits 0..5 = lane bits, bit6 = hi&1, bit7 = hi>>1.

template<int Q>
__device__ __forceinline__ void rzry(float (&sr)[4], float (&si)[4],
                                     const float* __restrict__ sQc,
                                     const float* __restrict__ sQs,
                                     int base, int lane) {
    constexpr int B = 7 - Q;
    // ---- RZ ----
    {
        float cz = sQc[base + 2 * Q], szv = sQs[base + 2 * Q];
        if constexpr (B < 6) {
            float sg = ((lane >> B) & 1) ? szv : -szv;
#pragma unroll
            for (int hi = 0; hi < 4; hi++) {
                float nr = sr[hi] * cz - si[hi] * sg;
                float ni = sr[hi] * sg + si[hi] * cz;
                sr[hi] = nr; si[hi] = ni;
            }
        } else {
#pragma unroll
            for (int hi = 0; hi < 4; hi++) {
                int bit = (B == 6) ? (hi & 1) : (hi >> 1);
                float sg = bit ? szv : -szv;
                float nr = sr[hi] * cz - si[hi] * sg;
                float ni = sr[hi] * sg + si[hi] * cz;
                sr[hi] = nr; si[hi] = ni;
            }
        }
    }
    // ---- RY ----
    {
        float cy = sQc[base + 2 * Q + 1], sy = sQs[base + 2 * Q + 1];
        if constexpr (B < 6) {
            float sg = ((lane >> B) & 1) ? sy : -sy;
#pragma unroll
            for (int hi = 0; hi < 4; hi++) {
                float pr = sx<(1 << B)>(sr[hi], lane);
                float pi = sx<(1 << B)>(si[hi], lane);
                sr[hi] = fmaf(sg, pr, cy * sr[hi]);
                si[hi] = fmaf(sg, pi, cy * si[hi]);
            }
        } else if constexpr (B == 6) {
            // pairs (0,1),(2,3)
#pragma unroll
            for (int p = 0; p < 2; p++) {
                int a0 = 2 * p, a1 = 2 * p + 1;
                float nr0 = cy * sr[a0] - sy * sr[a1];
                float ni0 = cy * si[a0] - sy * si[a1];
                float nr1 = sy * sr[a0] + cy * sr[a1];
                float ni1 = sy * si[a0] + cy * si[a1];
                sr[a0] = nr0; si[a0] = ni0; sr[a1] = nr1; si[a1] = ni1;
            }
        } else {
            // pairs (0,2),(1,3)
#pragma unroll
            for (int p = 0; p < 2; p++) {
                int a0 = p, a1 = p + 2;
                float nr0 = cy * sr[a0] - sy * sr[a1];
                float ni0 = cy * si[a0] - sy * si[a1];
                float nr1 = sy * sr[a0] + cy * sr[a1];
                float ni1 = sy * si[a0] + cy * si[a1];
                sr[a0] = nr0; si[a0] = ni0; sr[a1] = nr1; si[a1] = ni1;
            }
        }
    }
}

template<int BT>
__device__ __forceinline__ void cx_lane(float (&sr)[4], float (&si)[4], int lane) {
    bool ctrl = (lane >> (BT + 1)) & 1;
#pragma unroll
    for (int hi = 0; hi < 4; hi++) {
        float pr = sx<(1 << BT)>(sr[hi], lane);
        float pi = sx<(1 << BT)>(si[hi], lane);
        sr[hi] = ctrl ? pr : sr[hi];
        si[hi] = ctrl ? pi : si[hi];
    }
}

__global__ __launch_bounds__(THREADS) void hqcl_kernel(
    const float* __restrict__ x,     // (B,16)
    const float* __restrict__ w1,    // (256,16)
    const float* __restrict__ b1,    // (256)
    const float* __restrict__ w2,    // (8,256)
    const float* __restrict__ b2,    // (8)
    const float* __restrict__ qp,    // (48)
    const float* __restrict__ dw1,   // (256,1)
    const float* __restrict__ db1,   // (256)
    const float* __restrict__ dw2,   // (1,256)
    const float* __restrict__ db2,   // (1)
    float* __restrict__ out, int B)
{
    __shared__ float sQc[NPARAM], sQs[NPARAM];

    const int t = threadIdx.x;
    if (t < NPARAM) {
        float s, c;
        __sincosf(qp[t] * 0.5f, &s, &c);
        sQc[t] = c; sQs[t] = s;
    }
    __syncthreads();

    const int lane = t & 63;
    const int row  = blockIdx.x * WAVES_PER_BLOCK + (t >> 6);
    if (row >= B) return;

    // ---- encoder: h = relu(x @ W1^T + b1) ----
    const float4* xp = (const float4*)(x + row * FDIM);
    float4 x0 = xp[0], x1 = xp[1], x2 = xp[2], x3 = xp[3];

    float hreg[4];
#pragma unroll
    for (int m = 0; m < 4; m++) {
        int j = lane + 64 * m;
        const float4* wp = (const float4*)(w1 + j * FDIM);
        float4 wa = wp[0], wb = wp[1], wc = wp[2], wd = wp[3];
        float acc = b1[j];
        acc = fmaf(x0.x, wa.x, acc); acc = fmaf(x0.y, wa.y, acc);
        acc = fmaf(x0.z, wa.z, acc); acc = fmaf(x0.w, wa.w, acc);
        acc = fmaf(x1.x, wb.x, acc); acc = fmaf(x1.y, wb.y, acc);
        acc = fmaf(x1.z, wb.z, acc); acc = fmaf(x1.w, wb.w, acc);
        acc = fmaf(x2.x, wc.x, acc); acc = fmaf(x2.y, wc.y, acc);
        acc = fmaf(x2.z, wc.z, acc); acc = fmaf(x2.w, wc.w, acc);
        acc = fmaf(x3.x, wd.x, acc); acc = fmaf(x3.y, wd.y, acc);
        acc = fmaf(x3.z, wd.z, acc); acc = fmaf(x3.w, wd.w, acc);
        hreg[m] = fmaxf(acc, 0.f);
    }

    // ---- angles = tanh(h @ W2^T + b2) * pi ----
    float c0[NQ], s0[NQ];
#pragma unroll
    for (int q = 0; q < NQ; q++) {
        float a = 0.f;
#pragma unroll
        for (int m = 0; m < 4; m++)
            a = fmaf(hreg[m], w2[q * HDIM + lane + 64 * m], a);
        a = wred(a, lane);
        float ang = tanhf(a + b2[q]) * 3.14159265358979323846f;
        __sincosf(ang * 0.5f, &s0[q], &c0[q]);
    }

    // ---- initial 8 RYs on |0..0> -> product state ----
    float pl = 1.f;
#pragma unroll
    for (int b = 0; b < 6; b++) {
        int q = 7 - b;
        pl *= ((lane >> b) & 1) ? s0[q] : c0[q];
    }
    float sr[4], si[4];
    sr[0] = pl * c0[1] * c0[0];
    sr[1] = pl * s0[1] * c0[0];
    sr[2] = pl * c0[1] * s0[0];
    sr[3] = pl * s0[1] * s0[0];
#pragma unroll
    for (int hi = 0; hi < 4; hi++) si[hi] = 0.f;

    // ---- circuit ----
#pragma unroll
    for (int layer = 0; layer < DEPTH; layer++) {
        const int base = layer * 2 * NQ;
        rzry<0>(sr, si, sQc, sQs, base, lane);
        rzry<1>(sr, si, sQc, sQs, base, lane);
        rzry<2>(sr, si, sQc, sQs, base, lane);
        rzry<3>(sr, si, sQc, sQs, base, lane);
        rzry<4>(sr, si, sQc, sQs, base, lane);
        rzry<5>(sr, si, sQc, sQs, base, lane);
        rzry<6>(sr, si, sQc, sQs, base, lane);
        rzry<7>(sr, si, sQc, sQs, base, lane);

        // CX(0,1): ctrl bit7, tgt bit6 -> swap regs 2,3
        {
            float tr = sr[2], ti = si[2];
            sr[2] = sr[3]; si[2] = si[3];
            sr[3] = tr;    si[3] = ti;
        }
        // CX(1,2): ctrl bit6 (hi&1), tgt bit5 -> regs 1,3 xor32
        sr[1] = sx<32>(sr[1], lane); si[1] = sx<32>(si[1], lane);
        sr[3] = sx<32>(sr[3], lane); si[3] = sx<32>(si[3], lane);
        // CX(2..6, +1): ctrl lane bit bt+1, tgt lane bit bt
        cx_lane<4>(sr, si, lane);
        cx_lane<3>(sr, si, lane);
        cx_lane<2>(sr, si, lane);
        cx_lane<1>(sr, si, lane);
        cx_lane<0>(sr, si, lane);
        // CX(7,0): ctrl lane bit0, tgt bit7 -> swap (0,2),(1,3) where ctrl
        {
            bool ctrl = lane & 1;
            float t0r = sr[0], t0i = si[0], t1r = sr[1], t1i = si[1];
            sr[0] = ctrl ? sr[2] : sr[0]; si[0] = ctrl ? si[2] : si[0];
            sr[2] = ctrl ? t0r : sr[2];   si[2] = ctrl ? t0i : si[2];
            sr[1] = ctrl ? sr[3] : sr[1]; si[1] = ctrl ? si[3] : si[1];
            sr[3] = ctrl ? t1r : sr[3];   si[3] = ctrl ? t1i : si[3];
        }
    }

    // ---- <Z_0>: + for hi in {0,1}, - for hi in {2,3} ----
    float e = sr[0] * sr[0] + si[0] * si[0] + sr[1] * sr[1] + si[1] * si[1]
            - sr[2] * sr[2] - si[2] * si[2] - sr[3] * sr[3] - si[3] * si[3];
    e = wred(e, lane);

    // ---- decoder ----
    float acc = 0.f;
#pragma unroll
    for (int m = 0; m < 4; m++) {
        int j = lane + 64 * m;
        float d = fmaxf(fmaf(e, dw1[j], db1[j]), 0.f);
        acc = fmaf(d, dw2[j], acc);
    }
    acc = wred(acc, lane);
    if (lane == 0) out[row] = 1.f / (1.f + __expf(-(acc + db2[0])));
}

extern "C" void kernel_launch(void* const* d_in, const int* in_sizes, int n_in,
                              void* d_out, int out_size, void* d_ws, size_t ws_size,
                              hipStream_t stream) {
    const float* x   = (const float*)d_in[0];
    const float* w1  = (const float*)d_in[1];
    const float* b1  = (const float*)d_in[2];
    const float* w2  = (const float*)d_in[3];
    const float* b2  = (const float*)d_in[4];
    const float* qp  = (const float*)d_in[5];
    const float* dw1 = (const float*)d_in[6];
    const float* db1 = (const float*)d_in[7];
    const float* dw2 = (const float*)d_in[8];
    const float* db2 = (const float*)d_in[9];
    float* out = (float*)d_out;

    const int B = in_sizes[0] / FDIM;
    const int grid = (B + WAVES_PER_BLOCK - 1) / WAVES_PER_BLOCK;
    hqcl_kernel<<<grid, THREADS, 0, stream>>>(x, w1, b1, w2, b2, qp, dw1, db1, dw2, db2, out, B);
}

// Round 4
// 42.861 us; speedup vs baseline: 2.0246x; 1.4316x over previous
//
#include <hip/hip_runtime.h>
#include <math.h>

#define NQ 8
#define DEPTH 3
#define FDIM 16
#define HDIM 256
#define WAVES_PER_BLOCK 4
#define THREADS (WAVES_PER_BLOCK * 64)
#define NGATE (NQ * DEPTH)        // 24 (RZ,RY) pairs
#define PI_F 3.14159265358979323846f

// ---------------- cross-lane xor shuffles ----------------
template<int CTRL>
__device__ __forceinline__ float dpp1(float v) {
    return __int_as_float(__builtin_amdgcn_update_dpp(
        0, __float_as_int(v), CTRL, 0xF, 0xF, true));
}

// low-4-bit xor masks via DPP chains (quad_perm / row_half_mirror=xor7 /
// row_ror:8=xor8 / row_mirror=xor15); xor masks compose by XOR.
template<int M4>
__device__ __forceinline__ float shuf4(float v) {
    if constexpr (M4 == 0)  return v;
    else if constexpr (M4 == 1)  return dpp1<0xB1>(v);
    else if constexpr (M4 == 2)  return dpp1<0x4E>(v);
    else if constexpr (M4 == 3)  return dpp1<0x1B>(v);
    else if constexpr (M4 == 4)  return dpp1<0x1B>(dpp1<0x141>(v));
    else if constexpr (M4 == 5)  return dpp1<0x4E>(dpp1<0x141>(v));
    else if constexpr (M4 == 6)  return dpp1<0xB1>(dpp1<0x141>(v));
    else if constexpr (M4 == 7)  return dpp1<0x141>(v);
    else if constexpr (M4 == 8)  return dpp1<0x128>(v);
    else if constexpr (M4 == 9)  return dpp1<0xB1>(dpp1<0x128>(v));
    else if constexpr (M4 == 10) return dpp1<0x4E>(dpp1<0x128>(v));
    else if constexpr (M4 == 11) return dpp1<0x1B>(dpp1<0x128>(v));
    else if constexpr (M4 == 12) return dpp1<0x1B>(dpp1<0x140>(v));
    else if constexpr (M4 == 13) return dpp1<0x4E>(dpp1<0x140>(v));
    else if constexpr (M4 == 14) return dpp1<0xB1>(dpp1<0x140>(v));
    else                         return dpp1<0x140>(v);   // 15
}

// general 6-bit xor shuffle: DPP (<16), ds_swizzle (16..31), ds_bpermute (>=32)
template<int ML>
__device__ __forceinline__ float shuf(float v, int lane) {
    if constexpr (ML == 0) {
        return v;
    } else if constexpr (ML >= 32) {
        int addr = (lane ^ ML) << 2;
        return __int_as_float(__builtin_amdgcn_ds_bpermute(addr, __float_as_int(v)));
    } else if constexpr (ML >= 16) {
        return __int_as_float(__builtin_amdgcn_ds_swizzle(
            __float_as_int(v), (ML << 10) | 0x1F));   // BitMode xor=ML, and=0x1F
    } else {
        return shuf4<ML>(v);
    }
}

// permlane-based xor16/32 for latency-critical reductions (verified r3)
__device__ __forceinline__ float px16(float v, int lane) {
#if __has_builtin(__builtin_amdgcn_permlane16_swap)
    auto r = __builtin_amdgcn_permlane16_swap(__float_as_int(v), __float_as_int(v), false, false);
    return __int_as_float((lane & 16) ? r[0] : r[1]);
#else
    return __shfl_xor(v, 16, 64);
#endif
}
__device__ __forceinline__ float px32(float v, int lane) {
#if __has_builtin(__builtin_amdgcn_permlane32_swap)
    auto r = __builtin_amdgcn_permlane32_swap(__float_as_int(v), __float_as_int(v), false, false);
    return __int_as_float((lane & 32) ? r[0] : r[1]);
#else
    return __shfl_xor(v, 32, 64);
#endif
}

__device__ __forceinline__ float wred(float v, int lane) {
    v += shuf4<1>(v);
    v += shuf4<2>(v);
    v += shuf4<4>(v);
    v += shuf4<8>(v);
    v += px16(v, lane);
    v += px32(v, lane);
    return v;
}

__device__ __forceinline__ float fast_tanh(float y) {
    float ex = __expf(2.f * y);                       // inf for large y -> t=1
    return 1.f - 2.f * __builtin_amdgcn_rcpf(ex + 1.f);
}

// ---------------- relabeled gate ----------------
// Physical storage never permuted. Layer-l gates use pair-mask M = A^l*e_b and
// parity row R = row_b(A^{-l}), both 8-bit compile-time constants over
// x = (hi<<6)|lane.  RZ: amp *= (cz + i*sgz), sgz = p? sz : -sz.
// RY: amp = cy*amp + sgy*partner, partner at x ^ M, sgy = p? sy : -sy.
template<int M, int R>
__device__ __forceinline__ void gate2(float (&sr)[4], float (&si)[4],
                                      float cz, float szv, float cy, float sy,
                                      int lane) {
    constexpr int ML = M & 63, MH = (M >> 6) & 3;
    constexpr int RL = R & 63, RH = (R >> 6) & 3;
    bool p0;
    if constexpr (RL == 0)                 p0 = false;
    else if constexpr ((RL & (RL-1)) == 0) p0 = (lane & RL) != 0;
    else                                   p0 = (__popc(lane & RL) & 1) != 0;
    float sgz = p0 ? szv : -szv;
    float sgy = p0 ? sy  : -sy;
    // RZ (diagonal phase)
#pragma unroll
    for (int hi = 0; hi < 4; hi++) {
        const bool f = (__builtin_popcount(hi & RH) & 1) != 0;   // folds per-hi
        float z = f ? -sgz : sgz;
        float nr = fmaf(sr[hi], cz, -(si[hi] * z));
        float ni = fmaf(si[hi], cz,  (sr[hi] * z));
        sr[hi] = nr; si[hi] = ni;
    }
    // RY partners from post-RZ values
    float pr[4], pi[4];
#pragma unroll
    for (int hi = 0; hi < 4; hi++) {
        pr[hi] = shuf<ML>(sr[hi ^ MH], lane);
        pi[hi] = shuf<ML>(si[hi ^ MH], lane);
    }
#pragma unroll
    for (int hi = 0; hi < 4; hi++) {
        const bool f = (__builtin_popcount(hi & RH) & 1) != 0;
        float yv = f ? -sgy : sgy;
        sr[hi] = fmaf(yv, pr[hi], cy * sr[hi]);
        si[hi] = fmaf(yv, pi[hi], cy * si[hi]);
    }
}

__global__ __launch_bounds__(THREADS) void hqcl_kernel(
    const float* __restrict__ x,     // (B,16)
    const float* __restrict__ w1,    // (256,16)
    const float* __restrict__ b1,    // (256)
    const float* __restrict__ w2,    // (8,256)
    const float* __restrict__ b2,    // (8)
    const float* __restrict__ qp,    // (48)
    const float* __restrict__ dw1,   // (256,1)
    const float* __restrict__ db1,   // (256)
    const float* __restrict__ dw2,   // (1,256)
    const float* __restrict__ db2,   // (1)
    float* __restrict__ out, int B)
{
    __shared__ float4 sG4[NGATE];    // (cz,sz,cy,sy) per gate; gate g: qp[2g], qp[2g+1]

    const int t = threadIdx.x;
    if (t < 2 * NGATE) {
        float s, c;
        __sincosf(qp[t] * 0.5f, &s, &c);
        float* p = (float*)&sG4[t >> 1] + 2 * (t & 1);
        p[0] = c; p[1] = s;
    }
    __syncthreads();

    const int lane = t & 63;
    const int row  = blockIdx.x * WAVES_PER_BLOCK + (t >> 6);
    if (row >= B) return;

    // ---- encoder: h = relu(x @ W1^T + b1) ----
    const float4* xp = (const float4*)(x + row * FDIM);
    float4 x0 = xp[0], x1 = xp[1], x2 = xp[2], x3 = xp[3];

    float hreg[4];
#pragma unroll
    for (int m = 0; m < 4; m++) {
        int j = lane + 64 * m;
        const float4* wp = (const float4*)(w1 + j * FDIM);
        float4 wa = wp[0], wb = wp[1], wc = wp[2], wd = wp[3];
        float acc = b1[j];
        acc = fmaf(x0.x, wa.x, acc); acc = fmaf(x0.y, wa.y, acc);
        acc = fmaf(x0.z, wa.z, acc); acc = fmaf(x0.w, wa.w, acc);
        acc = fmaf(x1.x, wb.x, acc); acc = fmaf(x1.y, wb.y, acc);
        acc = fmaf(x1.z, wb.z, acc); acc = fmaf(x1.w, wb.w, acc);
        acc = fmaf(x2.x, wc.x, acc); acc = fmaf(x2.y, wc.y, acc);
        acc = fmaf(x2.z, wc.z, acc); acc = fmaf(x2.w, wc.w, acc);
        acc = fmaf(x3.x, wd.x, acc); acc = fmaf(x3.y, wd.y, acc);
        acc = fmaf(x3.z, wd.z, acc); acc = fmaf(x3.w, wd.w, acc);
        hreg[m] = fmaxf(acc, 0.f);
    }

    // ---- angles = tanh(h @ W2^T + b2) * pi ----
    float c0[NQ], s0[NQ];
#pragma unroll
    for (int q = 0; q < NQ; q++) {
        float a = 0.f;
#pragma unroll
        for (int m = 0; m < 4; m++)
            a = fmaf(hreg[m], w2[q * HDIM + lane + 64 * m], a);
        a = wred(a, lane);
        float ang = fast_tanh(a + b2[q]) * PI_F;
        __sincosf(ang * 0.5f, &s0[q], &c0[q]);
    }

    // ---- initial 8 RYs on |0..0> -> product state ----
    // amp index x = hi*64 + lane; qubit q <-> bit (7-q)
    float pl = 1.f;
#pragma unroll
    for (int b = 0; b < 6; b++) {
        int q = 7 - b;
        pl *= ((lane >> b) & 1) ? s0[q] : c0[q];
    }
    float sr[4], si[4];
    sr[0] = pl * c0[1] * c0[0];
    sr[1] = pl * s0[1] * c0[0];
    sr[2] = pl * c0[1] * s0[0];
    sr[3] = pl * s0[1] * s0[0];
#pragma unroll
    for (int hi = 0; hi < 4; hi++) si[hi] = 0.f;

    // ---- circuit: CX chains folded into per-layer masks (GF(2) relabeling) ----
    // A cols: C1 03 06 0C 18 30 60 C0 ; A^2 cols: 61 C2 05 0A 14 28 50 A0
    // A^-1 rows: FF FE FC F8 F0 E0 C0 7F ; A^-2 rows: AA 55 AB 57 AF 5F BF D5
#define GATE(L, Q, MM, RR) { float4 g4 = sG4[(L)*8 + (Q)]; \
        gate2<MM, RR>(sr, si, g4.x, g4.y, g4.z, g4.w, lane); }
    // layer 0 (identity labeling)
    GATE(0,0,0x80,0x80) GATE(0,1,0x40,0x40) GATE(0,2,0x20,0x20) GATE(0,3,0x10,0x10)
    GATE(0,4,0x08,0x08) GATE(0,5,0x04,0x04) GATE(0,6,0x02,0x02) GATE(0,7,0x01,0x01)
    // layer 1 (masks = cols of A, parities = rows of A^-1)
    GATE(1,0,0xC0,0x7F) GATE(1,1,0x60,0xC0) GATE(1,2,0x30,0xE0) GATE(1,3,0x18,0xF0)
    GATE(1,4,0x0C,0xF8) GATE(1,5,0x06,0xFC) GATE(1,6,0x03,0xFE) GATE(1,7,0xC1,0xFF)
    // layer 2 (masks = cols of A^2, parities = rows of A^-2)
    GATE(2,0,0xA0,0xD5) GATE(2,1,0x50,0xBF) GATE(2,2,0x28,0x5F) GATE(2,3,0x14,0xAF)
    GATE(2,4,0x0A,0x57) GATE(2,5,0x05,0xAB) GATE(2,6,0xC2,0x55) GATE(2,7,0x61,0xAA)
#undef GATE

    // ---- <Z_0> with final labeling: sign = parity(x & 0x4C) (row7 of A^-3) ----
    float m0 = sr[0]*sr[0] + si[0]*si[0] + sr[2]*sr[2] + si[2]*si[2]; // hi&1==0
    float m1 = sr[1]*sr[1] + si[1]*si[1] + sr[3]*sr[3] + si[3]*si[3]; // hi&1==1
    bool pb = (__popc(lane & 0x0C) & 1) != 0;
    float e = pb ? (m1 - m0) : (m0 - m1);
    e = wred(e, lane);

    // ---- decoder ----
    float acc = 0.f;
#pragma unroll
    for (int m = 0; m < 4; m++) {
        int j = lane + 64 * m;
        float d = fmaxf(fmaf(e, dw1[j], db1[j]), 0.f);
        acc = fmaf(d, dw2[j], acc);
    }
    acc = wred(acc, lane);
    if (lane == 0) out[row] = 1.f / (1.f + __expf(-(acc + db2[0])));
}

extern "C" void kernel_launch(void* const* d_in, const int* in_sizes, int n_in,
                              void* d_out, int out_size, void* d_ws, size_t ws_size,
                              hipStream_t stream) {
    const float* x   = (const float*)d_in[0];
    const float* w1  = (const float*)d_in[1];
    const float* b1  = (const float*)d_in[2];
    const float* w2  = (const float*)d_in[3];
    const float* b2  = (const float*)d_in[4];
    const float* qp  = (const float*)d_in[5];
    const float* dw1 = (const float*)d_in[6];
    const float* db1 = (const float*)d_in[7];
    const float* dw2 = (const float*)d_in[8];
    const float* db2 = (const float*)d_in[9];
    float* out = (float*)d_out;

    const int B = in_sizes[0] / FDIM;
    const int grid = (B + WAVES_PER_BLOCK - 1) / WAVES_PER_BLOCK;
    hqcl_kernel<<<grid, THREADS, 0, stream>>>(x, w1, b1, w2, b2, qp, dw1, db1, dw2, db2, out, B);
}

// Round 5
// 39.340 us; speedup vs baseline: 2.2058x; 1.0895x over previous
//
#include <hip/hip_runtime.h>
#include <math.h>

#define NQ 8
#define DEPTH 3
#define FDIM 16
#define HDIM 256
#define WAVES_PER_BLOCK 4
#define THREADS (WAVES_PER_BLOCK * 64)
#define NGATE (NQ * DEPTH)        // 24 (RZ,RY) pairs
#define PI_F 3.14159265358979323846f

// ---------------- cross-lane xor shuffles ----------------
template<int CTRL>
__device__ __forceinline__ float dpp1(float v) {
    return __int_as_float(__builtin_amdgcn_update_dpp(
        0, __float_as_int(v), CTRL, 0xF, 0xF, true));
}

// single-DPP xor masks used by wred (VALU, lowest latency)
template<int M4>
__device__ __forceinline__ float shuf4(float v) {
    if constexpr (M4 == 1)  return dpp1<0xB1>(v);   // quad_perm xor1
    else if constexpr (M4 == 2)  return dpp1<0x4E>(v);   // quad_perm xor2
    else if constexpr (M4 == 4)  return dpp1<0x1B>(dpp1<0x141>(v)); // xor3 o xor7
    else if constexpr (M4 == 8)  return dpp1<0x128>(v);  // row_ror:8 == xor8
    else return v;
}

// general 6-bit xor shuffle on the LDS pipe (0 VALU slots):
// ds_swizzle BitMode for masks 1..31, ds_bpermute for masks with bit5 set.
template<int ML>
__device__ __forceinline__ float shuf(float v, int lane) {
    if constexpr (ML == 0) {
        return v;
    } else if constexpr (ML >= 32) {
        int addr = (lane ^ ML) << 2;   // CSE'd across the 8 uses per gate
        return __int_as_float(__builtin_amdgcn_ds_bpermute(addr, __float_as_int(v)));
    } else {
        return __int_as_float(__builtin_amdgcn_ds_swizzle(
            __float_as_int(v), (ML << 10) | 0x1F));   // xor=ML, and=0x1F
    }
}

// full 64-lane sum, all lanes receive the total.
// permlane*_swap trick: r[0]+r[1] == v + v[lane^K] for every lane (no select).
__device__ __forceinline__ float wred(float v, int lane) {
    v += shuf4<1>(v);
    v += shuf4<2>(v);
    v += shuf4<4>(v);
    v += shuf4<8>(v);
#if __has_builtin(__builtin_amdgcn_permlane16_swap)
    {
        auto r = __builtin_amdgcn_permlane16_swap(__float_as_int(v), __float_as_int(v), false, false);
        v = __int_as_float(r[0]) + __int_as_float(r[1]);
    }
#else
    v += __shfl_xor(v, 16, 64);
#endif
#if __has_builtin(__builtin_amdgcn_permlane32_swap)
    {
        auto r = __builtin_amdgcn_permlane32_swap(__float_as_int(v), __float_as_int(v), false, false);
        v = __int_as_float(r[0]) + __int_as_float(r[1]);
    }
#else
    v += __shfl_xor(v, 32, 64);
#endif
    return v;
}

__device__ __forceinline__ float fast_tanh(float y) {
    float ex = __expf(2.f * y);                       // inf for large y -> t=1
    return 1.f - 2.f * __builtin_amdgcn_rcpf(ex + 1.f);
}

// ---------------- relabeled gate ----------------
// Physical storage never permuted. Layer-l gates use pair-mask M = A^l*e_b and
// parity row R = row_b(A^{-l}), both 8-bit compile-time constants over
// x = (hi<<6)|lane.  RZ: amp *= (cz + i*sgz), sgz = p? sz : -sz.
// RY: amp = cy*amp + sgy*partner, partner at x ^ M, sgy = p? sy : -sy.
template<int M, int R>
__device__ __forceinline__ void gate2(float (&sr)[4], float (&si)[4],
                                      float cz, float szv, float cy, float sy,
                                      int lane) {
    constexpr int ML = M & 63, MH = (M >> 6) & 3;
    constexpr int RL = R & 63, RH = (R >> 6) & 3;
    bool p0;
    if constexpr (RL == 0)                 p0 = false;
    else if constexpr ((RL & (RL-1)) == 0) p0 = (lane & RL) != 0;
    else                                   p0 = (__popc(lane & RL) & 1) != 0;
    float sgz = p0 ? szv : -szv;
    float sgy = p0 ? sy  : -sy;
    // RZ (diagonal phase)
#pragma unroll
    for (int hi = 0; hi < 4; hi++) {
        const bool f = (__builtin_popcount(hi & RH) & 1) != 0;   // folds per-hi
        float z = f ? -sgz : sgz;
        float nr = fmaf(sr[hi], cz, -(si[hi] * z));
        float ni = fmaf(si[hi], cz,  (sr[hi] * z));
        sr[hi] = nr; si[hi] = ni;
    }
    // RY partners from post-RZ values
    float pr[4], pi[4];
#pragma unroll
    for (int hi = 0; hi < 4; hi++) {
        pr[hi] = shuf<ML>(sr[hi ^ MH], lane);
        pi[hi] = shuf<ML>(si[hi ^ MH], lane);
    }
#pragma unroll
    for (int hi = 0; hi < 4; hi++) {
        const bool f = (__builtin_popcount(hi & RH) & 1) != 0;
        float yv = f ? -sgy : sgy;
        sr[hi] = fmaf(yv, pr[hi], cy * sr[hi]);
        si[hi] = fmaf(yv, pi[hi], cy * si[hi]);
    }
}

__global__ __launch_bounds__(THREADS) void hqcl_kernel(
    const float* __restrict__ x,     // (B,16)
    const float* __restrict__ w1,    // (256,16)
    const float* __restrict__ b1,    // (256)
    const float* __restrict__ w2,    // (8,256)
    const float* __restrict__ b2,    // (8)
    const float* __restrict__ qp,    // (48)
    const float* __restrict__ dw1,   // (256,1)
    const float* __restrict__ db1,   // (256)
    const float* __restrict__ dw2,   // (1,256)
    const float* __restrict__ db2,   // (1)
    float* __restrict__ out, int B)
{
    __shared__ float4 sG4[NGATE];    // (cz,sz,cy,sy) per gate; gate g: qp[2g], qp[2g+1]

    const int t = threadIdx.x;
    if (t < 2 * NGATE) {
        float s, c;
        __sincosf(qp[t] * 0.5f, &s, &c);
        float* p = (float*)&sG4[t >> 1] + 2 * (t & 1);
        p[0] = c; p[1] = s;
    }
    __syncthreads();

    const int lane = t & 63;
    const int row  = blockIdx.x * WAVES_PER_BLOCK + (t >> 6);
    if (row >= B) return;

    // ---- encoder: h = relu(x @ W1^T + b1) ----
    const float4* xp = (const float4*)(x + row * FDIM);
    float4 x0 = xp[0], x1 = xp[1], x2 = xp[2], x3 = xp[3];

    float hreg[4];
#pragma unroll
    for (int m = 0; m < 4; m++) {
        int j = lane + 64 * m;
        const float4* wp = (const float4*)(w1 + j * FDIM);
        float4 wa = wp[0], wb = wp[1], wc = wp[2], wd = wp[3];
        float acc = b1[j];
        acc = fmaf(x0.x, wa.x, acc); acc = fmaf(x0.y, wa.y, acc);
        acc = fmaf(x0.z, wa.z, acc); acc = fmaf(x0.w, wa.w, acc);
        acc = fmaf(x1.x, wb.x, acc); acc = fmaf(x1.y, wb.y, acc);
        acc = fmaf(x1.z, wb.z, acc); acc = fmaf(x1.w, wb.w, acc);
        acc = fmaf(x2.x, wc.x, acc); acc = fmaf(x2.y, wc.y, acc);
        acc = fmaf(x2.z, wc.z, acc); acc = fmaf(x2.w, wc.w, acc);
        acc = fmaf(x3.x, wd.x, acc); acc = fmaf(x3.y, wd.y, acc);
        acc = fmaf(x3.z, wd.z, acc); acc = fmaf(x3.w, wd.w, acc);
        hreg[m] = fmaxf(acc, 0.f);
    }

    // ---- angles = tanh(h @ W2^T + b2) * pi ----
    // angle/2 = tanh*pi/2 rad = tanh/4 revolutions -> native v_sin/v_cos range
    float c0[NQ], s0[NQ];
#pragma unroll
    for (int q = 0; q < NQ; q++) {
        float a = 0.f;
#pragma unroll
        for (int m = 0; m < 4; m++)
            a = fmaf(hreg[m], w2[q * HDIM + lane + 64 * m], a);
        a = wred(a, lane);
        float u = 0.25f * fast_tanh(a + b2[q]);
        float sv, cv;
        asm("v_sin_f32 %0, %1" : "=v"(sv) : "v"(u));
        asm("v_cos_f32 %0, %1" : "=v"(cv) : "v"(u));
        s0[q] = sv; c0[q] = cv;
    }

    // ---- initial 8 RYs on |0..0> -> product state ----
    // amp index x = hi*64 + lane; qubit q <-> bit (7-q)
    float pl = 1.f;
#pragma unroll
    for (int b = 0; b < 6; b++) {
        int q = 7 - b;
        pl *= ((lane >> b) & 1) ? s0[q] : c0[q];
    }
    float sr[4], si[4];
    sr[0] = pl * c0[1] * c0[0];
    sr[1] = pl * s0[1] * c0[0];
    sr[2] = pl * c0[1] * s0[0];
    sr[3] = pl * s0[1] * s0[0];
#pragma unroll
    for (int hi = 0; hi < 4; hi++) si[hi] = 0.f;

    // ---- circuit: CX chains folded into per-layer masks (GF(2) relabeling) ----
    // A cols: C1 03 06 0C 18 30 60 C0 ; A^2 cols: 61 C2 05 0A 14 28 50 A0
    // A^-1 rows: FF FE FC F8 F0 E0 C0 7F ; A^-2 rows: AA 55 AB 57 AF 5F BF D5
#define GATE(L, Q, MM, RR) { float4 g4 = sG4[(L)*8 + (Q)]; \
        gate2<MM, RR>(sr, si, g4.x, g4.y, g4.z, g4.w, lane); }
    // layer 0 (identity labeling)
    GATE(0,0,0x80,0x80) GATE(0,1,0x40,0x40) GATE(0,2,0x20,0x20) GATE(0,3,0x10,0x10)
    GATE(0,4,0x08,0x08) GATE(0,5,0x04,0x04) GATE(0,6,0x02,0x02) GATE(0,7,0x01,0x01)
    // layer 1 (masks = cols of A, parities = rows of A^-1)
    GATE(1,0,0xC0,0x7F) GATE(1,1,0x60,0xC0) GATE(1,2,0x30,0xE0) GATE(1,3,0x18,0xF0)
    GATE(1,4,0x0C,0xF8) GATE(1,5,0x06,0xFC) GATE(1,6,0x03,0xFE) GATE(1,7,0xC1,0xFF)
    // layer 2 (masks = cols of A^2, parities = rows of A^-2)
    GATE(2,0,0xA0,0xD5) GATE(2,1,0x50,0xBF) GATE(2,2,0x28,0x5F) GATE(2,3,0x14,0xAF)
    GATE(2,4,0x0A,0x57) GATE(2,5,0x05,0xAB) GATE(2,6,0xC2,0x55) GATE(2,7,0x61,0xAA)
#undef GATE

    // ---- <Z_0> with final labeling: sign = parity(x & 0x4C) (row7 of A^-3) ----
    float m0 = sr[0]*sr[0] + si[0]*si[0] + sr[2]*sr[2] + si[2]*si[2]; // hi&1==0
    float m1 = sr[1]*sr[1] + si[1]*si[1] + sr[3]*sr[3] + si[3]*si[3]; // hi&1==1
    bool pb = (__popc(lane & 0x0C) & 1) != 0;
    float e = pb ? (m1 - m0) : (m0 - m1);
    e = wred(e, lane);

    // ---- decoder ----
    float acc = 0.f;
#pragma unroll
    for (int m = 0; m < 4; m++) {
        int j = lane + 64 * m;
        float d = fmaxf(fmaf(e, dw1[j], db1[j]), 0.f);
        acc = fmaf(d, dw2[j], acc);
    }
    acc = wred(acc, lane);
    if (lane == 0) out[row] = 1.f / (1.f + __expf(-(acc + db2[0])));
}

extern "C" void kernel_launch(void* const* d_in, const int* in_sizes, int n_in,
                              void* d_out, int out_size, void* d_ws, size_t ws_size,
                              hipStream_t stream) {
    const float* x   = (const float*)d_in[0];
    const float* w1  = (const float*)d_in[1];
    const float* b1  = (const float*)d_in[2];
    const float* w2  = (const float*)d_in[3];
    const float* b2  = (const float*)d_in[4];
    const float* qp  = (const float*)d_in[5];
    const float* dw1 = (const float*)d_in[6];
    const float* db1 = (const float*)d_in[7];
    const float* dw2 = (const float*)d_in[8];
    const float* db2 = (const float*)d_in[9];
    float* out = (float*)d_out;

    const int B = in_sizes[0] / FDIM;
    const int grid = (B + WAVES_PER_BLOCK - 1) / WAVES_PER_BLOCK;
    hqcl_kernel<<<grid, THREADS, 0, stream>>>(x, w1, b1, w2, b2, qp, dw1, db1, dw2, db2, out, B);
}